// Round 8
// baseline (601.076 us; speedup 1.0000x reference)
//
#include <hip/hip_runtime.h>

#define NUM_RELS 19
#define NPB 256        // nodes per bucket (power of 2)
#define NPB_SHIFT 8
#define MAXB 400       // max buckets (N <= 102400)
#define PCAP 16        // partition stage capacity per bucket (flush in units of 8)

typedef _Float16 half8 __attribute__((ext_vector_type(8)));
typedef float floatx4 __attribute__((ext_vector_type(4)));

// ---------------- bucket histogram: bcnt[b] = #edges with dst in bucket b ----------------

__global__ __launch_bounds__(256) void bhist_kernel(const int* __restrict__ dst,
                                                    int* __restrict__ bcnt, int E, int B) {
    __shared__ int h[MAXB];
    for (int i = threadIdx.x; i < B; i += 256) h[i] = 0;
    __syncthreads();
    for (int e = blockIdx.x * blockDim.x + threadIdx.x; e < E; e += gridDim.x * blockDim.x)
        atomicAdd(&h[dst[e] >> NPB_SHIFT], 1);
    __syncthreads();
    for (int i = threadIdx.x; i < B; i += 256)
        if (h[i]) atomicAdd(&bcnt[i], h[i]);
}

// ---------------- bucket scan: pbase = exclusive scan of 8-aligned counts; gcur = pbase ----------------

__global__ __launch_bounds__(512) void bscan_kernel(const int* __restrict__ bcnt,
                                                    int* __restrict__ pbase,
                                                    int* __restrict__ gcur, int B) {
    __shared__ int lds[512];
    int t = threadIdx.x;
    int c = (t < B) ? ((bcnt[t] + 7) & ~7) : 0;
    lds[t] = c;
    __syncthreads();
    for (int off = 1; off < 512; off <<= 1) {
        int x = (t >= off) ? lds[t - off] : 0;
        __syncthreads();
        lds[t] += x;
        __syncthreads();
    }
    if (t < B) {
        int p = lds[t] - c;
        pbase[t] = p;
        gcur[t] = p;
    }
}

// ---------------- partition: bin edges into bucket regions with line-granular flushes ----------------

__global__ __launch_bounds__(512) void partition_kernel(
    const int* __restrict__ src, const int* __restrict__ dst, const int* __restrict__ etype,
    int* __restrict__ gcur, uint2* __restrict__ recs, int E, int B, int chunk) {
    __shared__ uint2 stage[MAXB * PCAP];  // 400*16*8B = 51.2KB
    __shared__ int scnt[MAXB];
    for (int i = threadIdx.x; i < B; i += 512) scnt[i] = 0;
    __syncthreads();

    int e0 = blockIdx.x * chunk;
    int e1 = min(E, e0 + chunk);
    for (int base = e0; base < e1; base += 512) {
        int e = base + (int)threadIdx.x;
        if (e < e1) {
            int d = dst[e];
            uint2 rec;
            rec.x = ((unsigned)src[e] << 5) | (unsigned)etype[e];
            rec.y = (unsigned)d;
            int b = d >> NPB_SHIFT;
            int pos = atomicAdd(&scnt[b], 1);
            if (pos < PCAP) {
                stage[b * PCAP + pos] = rec;
            } else {  // spill valve
                int g = atomicAdd(&gcur[b], 1);
                recs[g] = rec;
            }
        }
        __syncthreads();
        for (int bb = threadIdx.x; bb < B; bb += 512) {
            int c = scnt[bb];
            if (c > PCAP) c = PCAP;
            int nf = c & ~7;
            if (nf) {
                int g = atomicAdd(&gcur[bb], nf);
                for (int i = 0; i < nf; ++i) recs[g + i] = stage[bb * PCAP + i];
                for (int i = 0; i < c - nf; ++i) stage[bb * PCAP + i] = stage[bb * PCAP + nf + i];
            }
            scnt[bb] = c - nf;
        }
        __syncthreads();
    }
    // drain remainders
    for (int bb = threadIdx.x; bb < B; bb += 512) {
        int c = scnt[bb];
        if (c > PCAP) c = PCAP;
        if (c) {
            int g = atomicAdd(&gcur[bb], c);
            for (int i = 0; i < c; ++i) recs[g + i] = stage[bb * PCAP + i];
        }
    }
}

// ---------------- Layer 1 per bucket: LDS (node,rel) counts -> h1 = relu(b1 + sum_r cnt*W1[r]) ----------------

__global__ __launch_bounds__(256) void blayer1_kernel(
    const uint2* __restrict__ recs, const int* __restrict__ pbase, const int* __restrict__ bcnt,
    const float* __restrict__ W1, const float* __restrict__ b1, float* __restrict__ h1, int N) {
    __shared__ int cnt[NPB * NUM_RELS];  // 19.4KB
    __shared__ float W1s[NUM_RELS * 32];
    __shared__ float b1s[32];
    for (int i = threadIdx.x; i < NPB * NUM_RELS; i += 256) cnt[i] = 0;
    for (int i = threadIdx.x; i < NUM_RELS * 32; i += 256) W1s[i] = W1[i];
    if (threadIdx.x < 32) b1s[threadIdx.x] = b1[threadIdx.x];
    __syncthreads();

    int b = blockIdx.x;
    int p0 = pbase[b], n = bcnt[b];
    for (int i = threadIdx.x; i < n; i += 256) {
        uint2 rec = recs[p0 + i];
        atomicAdd(&cnt[(rec.y & (NPB - 1)) * NUM_RELS + (rec.x & 31)], 1);
    }
    __syncthreads();

    int o = threadIdx.x & 31, hw = threadIdx.x >> 5;  // 8 half-waves
    int v0 = b << NPB_SHIFT;
    for (int k = hw; k < NPB; k += 8) {
        int v = v0 + k;
        if (v >= N) break;
        float acc = b1s[o];
        const int* cp = &cnt[k * NUM_RELS];
#pragma unroll
        for (int r = 0; r < NUM_RELS; ++r) acc += (float)cp[r] * W1s[r * 32 + o];
        h1[(size_t)v * 32 + o] = fmaxf(acc, 0.f);
    }
}

// ---------------- W2 -> f16 B-fragment swizzle (round-6 verified) ----------------

__global__ void w2swz_kernel(const float* __restrict__ W2, _Float16* __restrict__ W2F) {
    int idx = blockIdx.x * blockDim.x + threadIdx.x;
    if (idx >= NUM_RELS * 2 * 64 * 8) return;
    int j = idx & 7, lane = (idx >> 3) & 63, nt = (idx >> 9) & 1, r = idx >> 10;
    int k = (lane >> 4) * 8 + j, n = nt * 16 + (lane & 15);
    W2F[idx] = (_Float16)W2[r * 1024 + k * 32 + n];
}

// ---------------- Transform via MFMA: g[r] = h1 @ W2[r]  (f16 output; round-6 verified) ----------------

__global__ __launch_bounds__(256) void transform_kernel(
    const float* __restrict__ h1, const _Float16* __restrict__ W2F,
    _Float16* __restrict__ g, int N) {
    int lane = threadIdx.x & 63;
    int tile = blockIdx.x * 4 + (threadIdx.x >> 6);
    int v0 = tile * 16;
    if (v0 >= N) return;

    const float* hrow = h1 + (size_t)(v0 + (lane & 15)) * 32 + (lane >> 4) * 8;
    float4 p0 = *(const float4*)hrow;
    float4 p1 = *(const float4*)(hrow + 4);
    half8 a;
    a[0] = (_Float16)p0.x; a[1] = (_Float16)p0.y; a[2] = (_Float16)p0.z; a[3] = (_Float16)p0.w;
    a[4] = (_Float16)p1.x; a[5] = (_Float16)p1.y; a[6] = (_Float16)p1.z; a[7] = (_Float16)p1.w;

    floatx4 zero = {0.f, 0.f, 0.f, 0.f};
    int row = (lane >> 4) * 4;
    int col = lane & 15;
    for (int r = 0; r < NUM_RELS; ++r) {
        _Float16* gbase = g + ((size_t)r * N + v0) * 32;
#pragma unroll
        for (int nt = 0; nt < 2; ++nt) {
            half8 bfrag = *(const half8*)(W2F + ((r * 2 + nt) * 64 + lane) * 8);
            floatx4 d = __builtin_amdgcn_mfma_f32_16x16x32_f16(a, bfrag, zero, 0, 0, 0);
#pragma unroll
            for (int reg = 0; reg < 4; ++reg) {
                gbase[(row + reg) * 32 + nt * 16 + col] = (_Float16)d[reg];
            }
        }
    }
}

// ---------------- Aggregate per bucket + fused layer 3 (edge23-style record tiles) ----------------
// Per half-wave: load 32 records COALESCED (one uint2 load), shfl-broadcast each from registers,
// 4 independent g-row loads in flight per group, values die into conflict-free ds_add.
// Round-7 failure mode avoided: no per-record broadcast loads, no long-lived buffers (VGPR ~48).

__global__ __launch_bounds__(1024) void agg_kernel(
    const _Float16* __restrict__ g, const uint2* __restrict__ recs,
    const int* __restrict__ pbase, const int* __restrict__ bcnt,
    const float* __restrict__ b2, const float* __restrict__ W3, const float* __restrict__ b3,
    float* __restrict__ out, int N) {
    __shared__ float z2[NPB * 32];  // 32KB
    __shared__ float W3s[1024];
    __shared__ float b3s[32];
    if (threadIdx.x < 1024) W3s[threadIdx.x] = W3[threadIdx.x];
    if (threadIdx.x < 32) b3s[threadIdx.x] = b3[threadIdx.x];
    for (int i = threadIdx.x; i < NPB * 32; i += 1024) z2[i] = b2[i & 31];
    __syncthreads();

    int b = blockIdx.x;
    int p0 = pbase[b], n = bcnt[b];
    int o = threadIdx.x & 31, hw = threadIdx.x >> 5;  // 32 half-waves
    const size_t sN32 = (size_t)N * 32;
    const uint2* rp = recs + p0;

    for (int base = hw * 32; base < n; base += 32 * 32) {
        int idx = base + o;
        unsigned mx_l = 0, my_l = 0;
        if (idx < n) {
            uint2 rec = rp[idx];  // coalesced: 32 records per half-wave in ONE load
            mx_l = rec.x;
            my_l = rec.y;
        }
        int cnt = min(32, n - base);
        int j = 0;
        for (; j + 4 <= cnt; j += 4) {
            unsigned mx0 = __shfl((int)mx_l, j + 0, 32), my0 = __shfl((int)my_l, j + 0, 32);
            unsigned mx1 = __shfl((int)mx_l, j + 1, 32), my1 = __shfl((int)my_l, j + 1, 32);
            unsigned mx2 = __shfl((int)mx_l, j + 2, 32), my2 = __shfl((int)my_l, j + 2, 32);
            unsigned mx3 = __shfl((int)mx_l, j + 3, 32), my3 = __shfl((int)my_l, j + 3, 32);
            float x0 = (float)g[(mx0 & 31) * sN32 + (mx0 >> 5) * 32 + o];
            float x1 = (float)g[(mx1 & 31) * sN32 + (mx1 >> 5) * 32 + o];
            float x2 = (float)g[(mx2 & 31) * sN32 + (mx2 >> 5) * 32 + o];
            float x3 = (float)g[(mx3 & 31) * sN32 + (mx3 >> 5) * 32 + o];
            atomicAdd(&z2[(my0 & (NPB - 1)) * 32 + o], x0);
            atomicAdd(&z2[(my1 & (NPB - 1)) * 32 + o], x1);
            atomicAdd(&z2[(my2 & (NPB - 1)) * 32 + o], x2);
            atomicAdd(&z2[(my3 & (NPB - 1)) * 32 + o], x3);
        }
        for (; j < cnt; ++j) {
            unsigned mx = __shfl((int)mx_l, j, 32), my = __shfl((int)my_l, j, 32);
            float x = (float)g[(mx & 31) * sN32 + (mx >> 5) * 32 + o];
            atomicAdd(&z2[(my & (NPB - 1)) * 32 + o], x);
        }
    }
    __syncthreads();

    int v0 = b << NPB_SHIFT;
    for (int k = hw; k < NPB; k += 32) {
        int v = v0 + k;
        if (v >= N) break;
        float h2v = fmaxf(z2[k * 32 + o], 0.f);
        float acc3 = b3s[o];
#pragma unroll
        for (int i = 0; i < 32; ++i) acc3 = fmaf(__shfl(h2v, i, 32), W3s[i * 32 + o], acc3);
        out[(size_t)v * 32 + o] = acc3;
    }
}

// ---------------- Host launcher ----------------

extern "C" void kernel_launch(void* const* d_in, const int* in_sizes, int n_in,
                              void* d_out, int out_size, void* d_ws, size_t ws_size,
                              hipStream_t stream) {
    const int* src   = (const int*)d_in[0];
    const int* dst   = (const int*)d_in[1];
    const int* etype = (const int*)d_in[2];
    const float* W1  = (const float*)d_in[4];
    const float* b1  = (const float*)d_in[5];
    const float* W2  = (const float*)d_in[6];
    const float* b2  = (const float*)d_in[7];
    const float* W3  = (const float*)d_in[8];
    const float* b3  = (const float*)d_in[9];
    float* out = (float*)d_out;

    int E = in_sizes[0];
    int N = out_size / 32;
    int B = (N + NPB - 1) >> NPB_SHIFT;  // 391 for N=100000

    char* ws = (char*)d_ws;
    size_t off = 0;
    auto alloc = [&](size_t bytes) {
        void* p = ws + off;
        off = (off + bytes + 255) & ~(size_t)255;
        return p;
    };
    float* h1     = (float*)alloc((size_t)N * 32 * 4);
    int* bcnt     = (int*)alloc((size_t)MAXB * 4);
    int* pbase    = (int*)alloc((size_t)MAXB * 4);
    int* gcur     = (int*)alloc((size_t)MAXB * 4);
    uint2* recs   = (uint2*)alloc(((size_t)E + 8 * MAXB + 64) * 8);
    _Float16* g   = (_Float16*)alloc((size_t)NUM_RELS * N * 32 * 2);
    _Float16* W2F = (_Float16*)alloc((size_t)NUM_RELS * 2 * 64 * 8 * 2);

    hipMemsetAsync(bcnt, 0, (size_t)B * 4, stream);
    bhist_kernel<<<256, 256, 0, stream>>>(dst, bcnt, E, B);
    bscan_kernel<<<1, 512, 0, stream>>>(bcnt, pbase, gcur, B);

    int chunk = (E + 127) / 128;
    partition_kernel<<<128, 512, 0, stream>>>(src, dst, etype, gcur, recs, E, B, chunk);

    blayer1_kernel<<<B, 256, 0, stream>>>(recs, pbase, bcnt, W1, b1, h1, N);

    w2swz_kernel<<<(NUM_RELS * 2 * 64 * 8 + 255) / 256, 256, 0, stream>>>(W2, W2F);
    int ntiles = (N + 15) / 16;
    transform_kernel<<<(ntiles + 3) / 4, 256, 0, stream>>>(h1, W2F, g, N);

    agg_kernel<<<B, 1024, 0, stream>>>(g, recs, pbase, bcnt, b2, W3, b3, out, N);
}

// Round 9
// 269.851 us; speedup vs baseline: 2.2274x; 2.2274x over previous
//
#include <hip/hip_runtime.h>

#define NUM_RELS 19
#define NPB 256        // nodes per bucket (power of 2)
#define NPB_SHIFT 8
#define MAXB 400       // max buckets (N <= 102400)
#define PCAP 16        // partition stage capacity per bucket (flush in units of 8)

typedef _Float16 half8 __attribute__((ext_vector_type(8)));
typedef float floatx4 __attribute__((ext_vector_type(4)));

// ---------------- bucket histogram: bcnt[b] = #edges with dst in bucket b ----------------

__global__ __launch_bounds__(256) void bhist_kernel(const int* __restrict__ dst,
                                                    int* __restrict__ bcnt, int E, int B) {
    __shared__ int h[MAXB];
    for (int i = threadIdx.x; i < B; i += 256) h[i] = 0;
    __syncthreads();
    for (int e = blockIdx.x * blockDim.x + threadIdx.x; e < E; e += gridDim.x * blockDim.x)
        atomicAdd(&h[dst[e] >> NPB_SHIFT], 1);
    __syncthreads();
    for (int i = threadIdx.x; i < B; i += 256)
        if (h[i]) atomicAdd(&bcnt[i], h[i]);
}

// ---------------- bucket scan: pbase = exclusive scan of 8-aligned counts; gcur = pbase ----------------

__global__ __launch_bounds__(512) void bscan_kernel(const int* __restrict__ bcnt,
                                                    int* __restrict__ pbase,
                                                    int* __restrict__ gcur, int B) {
    __shared__ int lds[512];
    int t = threadIdx.x;
    int c = (t < B) ? ((bcnt[t] + 7) & ~7) : 0;
    lds[t] = c;
    __syncthreads();
    for (int off = 1; off < 512; off <<= 1) {
        int x = (t >= off) ? lds[t - off] : 0;
        __syncthreads();
        lds[t] += x;
        __syncthreads();
    }
    if (t < B) {
        int p = lds[t] - c;
        pbase[t] = p;
        gcur[t] = p;
    }
}

// ---------------- partition: bin edges into bucket regions with line-granular flushes ----------------

__global__ __launch_bounds__(512) void partition_kernel(
    const int* __restrict__ src, const int* __restrict__ dst, const int* __restrict__ etype,
    int* __restrict__ gcur, uint2* __restrict__ recs, int E, int B, int chunk) {
    __shared__ uint2 stage[MAXB * PCAP];  // 400*16*8B = 51.2KB
    __shared__ int scnt[MAXB];
    for (int i = threadIdx.x; i < B; i += 512) scnt[i] = 0;
    __syncthreads();

    int e0 = blockIdx.x * chunk;
    int e1 = min(E, e0 + chunk);
    for (int base = e0; base < e1; base += 512) {
        int e = base + (int)threadIdx.x;
        if (e < e1) {
            int d = dst[e];
            uint2 rec;
            rec.x = ((unsigned)src[e] << 5) | (unsigned)etype[e];
            rec.y = (unsigned)d;
            int b = d >> NPB_SHIFT;
            int pos = atomicAdd(&scnt[b], 1);
            if (pos < PCAP) {
                stage[b * PCAP + pos] = rec;
            } else {  // spill valve
                int g = atomicAdd(&gcur[b], 1);
                recs[g] = rec;
            }
        }
        __syncthreads();
        for (int bb = threadIdx.x; bb < B; bb += 512) {
            int c = scnt[bb];
            if (c > PCAP) c = PCAP;
            int nf = c & ~7;
            if (nf) {
                int g = atomicAdd(&gcur[bb], nf);
                for (int i = 0; i < nf; ++i) recs[g + i] = stage[bb * PCAP + i];
                for (int i = 0; i < c - nf; ++i) stage[bb * PCAP + i] = stage[bb * PCAP + nf + i];
            }
            scnt[bb] = c - nf;
        }
        __syncthreads();
    }
    // drain remainders
    for (int bb = threadIdx.x; bb < B; bb += 512) {
        int c = scnt[bb];
        if (c > PCAP) c = PCAP;
        if (c) {
            int g = atomicAdd(&gcur[bb], c);
            for (int i = 0; i < c; ++i) recs[g + i] = stage[bb * PCAP + i];
        }
    }
}

// ---------------- bucket-local counting sort -> per-node CSR ----------------
// Per bucket: LDS per-node histogram + scan, then scatter recs -> recs2 (4B, node-sorted).
// Scatter writes are random ONLY within the bucket's ~16KB recs2 region -> L2 absorbs the
// line-granularity amplification (this is what made round-6's global scatter cost 105MB).
// Emits row_start/rend (rend needed: bucket bases are 8-padded, gaps hold poison).

__global__ __launch_bounds__(256) void bsort_kernel(
    const uint2* __restrict__ recs, const int* __restrict__ pbase, const int* __restrict__ bcnt,
    int* __restrict__ recs2, int* __restrict__ row_start, int* __restrict__ rend, int N) {
    __shared__ int hist[NPB];
    __shared__ int offs[NPB];
    __shared__ int cur[NPB];
    int b = blockIdx.x;
    int p0 = pbase[b], n = bcnt[b];
    int t = threadIdx.x;

    hist[t] = 0;
    __syncthreads();
    for (int i = t; i < n; i += 256) atomicAdd(&hist[recs[p0 + i].y & (NPB - 1)], 1);
    __syncthreads();
    int c = hist[t];
    offs[t] = c;
    __syncthreads();
    for (int off = 1; off < 256; off <<= 1) {
        int x = (t >= off) ? offs[t - off] : 0;
        __syncthreads();
        offs[t] += x;
        __syncthreads();
    }
    int start = p0 + offs[t] - c;  // exclusive
    cur[t] = start;
    int v = (b << NPB_SHIFT) + t;
    if (v < N) {
        row_start[v] = start;
        rend[v] = start + c;
    }
    __syncthreads();
    for (int i = t; i < n; i += 256) {
        uint2 rec = recs[p0 + i];
        int p = atomicAdd(&cur[rec.y & (NPB - 1)], 1);
        recs2[p] = (int)rec.x;
    }
}

// ---------------- Layer 1 per bucket: LDS (node,rel) counts -> h1 = relu(b1 + sum_r cnt*W1[r]) ----------------

__global__ __launch_bounds__(256) void blayer1_kernel(
    const uint2* __restrict__ recs, const int* __restrict__ pbase, const int* __restrict__ bcnt,
    const float* __restrict__ W1, const float* __restrict__ b1, float* __restrict__ h1, int N) {
    __shared__ int cnt[NPB * NUM_RELS];  // 19.4KB
    __shared__ float W1s[NUM_RELS * 32];
    __shared__ float b1s[32];
    for (int i = threadIdx.x; i < NPB * NUM_RELS; i += 256) cnt[i] = 0;
    for (int i = threadIdx.x; i < NUM_RELS * 32; i += 256) W1s[i] = W1[i];
    if (threadIdx.x < 32) b1s[threadIdx.x] = b1[threadIdx.x];
    __syncthreads();

    int b = blockIdx.x;
    int p0 = pbase[b], n = bcnt[b];
    for (int i = threadIdx.x; i < n; i += 256) {
        uint2 rec = recs[p0 + i];
        atomicAdd(&cnt[(rec.y & (NPB - 1)) * NUM_RELS + (rec.x & 31)], 1);
    }
    __syncthreads();

    int o = threadIdx.x & 31, hw = threadIdx.x >> 5;  // 8 half-waves
    int v0 = b << NPB_SHIFT;
    for (int k = hw; k < NPB; k += 8) {
        int v = v0 + k;
        if (v >= N) break;
        float acc = b1s[o];
        const int* cp = &cnt[k * NUM_RELS];
#pragma unroll
        for (int r = 0; r < NUM_RELS; ++r) acc += (float)cp[r] * W1s[r * 32 + o];
        h1[(size_t)v * 32 + o] = fmaxf(acc, 0.f);
    }
}

// ---------------- W2 -> f16 B-fragment swizzle (round-6 verified) ----------------

__global__ void w2swz_kernel(const float* __restrict__ W2, _Float16* __restrict__ W2F) {
    int idx = blockIdx.x * blockDim.x + threadIdx.x;
    if (idx >= NUM_RELS * 2 * 64 * 8) return;
    int j = idx & 7, lane = (idx >> 3) & 63, nt = (idx >> 9) & 1, r = idx >> 10;
    int k = (lane >> 4) * 8 + j, n = nt * 16 + (lane & 15);
    W2F[idx] = (_Float16)W2[r * 1024 + k * 32 + n];
}

// ---------------- Transform via MFMA: g[r] = h1 @ W2[r]  (f16 output; round-6 verified) ----------------

__global__ __launch_bounds__(256) void transform_kernel(
    const float* __restrict__ h1, const _Float16* __restrict__ W2F,
    _Float16* __restrict__ g, int N) {
    int lane = threadIdx.x & 63;
    int tile = blockIdx.x * 4 + (threadIdx.x >> 6);
    int v0 = tile * 16;
    if (v0 >= N) return;

    const float* hrow = h1 + (size_t)(v0 + (lane & 15)) * 32 + (lane >> 4) * 8;
    float4 p0 = *(const float4*)hrow;
    float4 p1 = *(const float4*)(hrow + 4);
    half8 a;
    a[0] = (_Float16)p0.x; a[1] = (_Float16)p0.y; a[2] = (_Float16)p0.z; a[3] = (_Float16)p0.w;
    a[4] = (_Float16)p1.x; a[5] = (_Float16)p1.y; a[6] = (_Float16)p1.z; a[7] = (_Float16)p1.w;

    floatx4 zero = {0.f, 0.f, 0.f, 0.f};
    int row = (lane >> 4) * 4;
    int col = lane & 15;
    for (int r = 0; r < NUM_RELS; ++r) {
        _Float16* gbase = g + ((size_t)r * N + v0) * 32;
#pragma unroll
        for (int nt = 0; nt < 2; ++nt) {
            half8 bfrag = *(const half8*)(W2F + ((r * 2 + nt) * 64 + lane) * 8);
            floatx4 d = __builtin_amdgcn_mfma_f32_16x16x32_f16(a, bfrag, zero, 0, 0, 0);
#pragma unroll
            for (int reg = 0; reg < 4; ++reg) {
                gbase[(row + reg) * 32 + nt * 16 + col] = (_Float16)d[reg];
            }
        }
    }
}

// ---------------- Edge phase + layer 3 fused (round-6 proven shape: register accumulation) ----------------
// Per 32-lane half-wave: one node, lane = output channel o. Records for the node are contiguous
// [row_start[v], rend[v]). Per edge: coalesced rec-tile load + shfl broadcast + ONE g-row load
// + register add. NO LDS atomics in the loop (rounds 7/8 showed those serialize the scheduler).

__global__ __launch_bounds__(1024) void edge23_kernel(
    const _Float16* __restrict__ g, const int* __restrict__ row_start,
    const int* __restrict__ rend, const int* __restrict__ recs2,
    const float* __restrict__ b2, const float* __restrict__ W3, const float* __restrict__ b3,
    float* __restrict__ out, int N) {
    __shared__ float W3s[1024];
    __shared__ float b2s[32], b3s[32];
    W3s[threadIdx.x] = W3[threadIdx.x];
    if (threadIdx.x < 32) {
        b2s[threadIdx.x] = b2[threadIdx.x];
        b3s[threadIdx.x] = b3[threadIdx.x];
    }
    __syncthreads();

    int o = threadIdx.x & 31;
    int hw = blockIdx.x * 32 + (threadIdx.x >> 5);  // node id
    if (hw >= N) return;
    int start = row_start[hw], end = rend[hw];
    const size_t sN32 = (size_t)N * 32;

    float acc = b2s[o];
    for (int base = start; base < end; base += 32) {
        int idx = base + o;
        int m_l = (idx < end) ? recs2[idx] : 0;  // coalesced packed (src<<5|etype)
        int cnt = min(32, end - base);
        int j = 0;
        for (; j + 4 <= cnt; j += 4) {
            int m0 = __shfl(m_l, j + 0, 32);
            int m1 = __shfl(m_l, j + 1, 32);
            int m2 = __shfl(m_l, j + 2, 32);
            int m3 = __shfl(m_l, j + 3, 32);
            float x0 = (float)g[(size_t)(m0 & 31) * sN32 + (unsigned)(m0 >> 5) * 32 + o];
            float x1 = (float)g[(size_t)(m1 & 31) * sN32 + (unsigned)(m1 >> 5) * 32 + o];
            float x2 = (float)g[(size_t)(m2 & 31) * sN32 + (unsigned)(m2 >> 5) * 32 + o];
            float x3 = (float)g[(size_t)(m3 & 31) * sN32 + (unsigned)(m3 >> 5) * 32 + o];
            acc += (x0 + x1) + (x2 + x3);
        }
        for (; j < cnt; ++j) {
            int m = __shfl(m_l, j, 32);
            acc += (float)g[(size_t)(m & 31) * sN32 + (unsigned)(m >> 5) * 32 + o];
        }
    }
    float h2v = fmaxf(acc, 0.f);

    float acc3 = b3s[o];
#pragma unroll
    for (int i = 0; i < 32; ++i) {
        float hi = __shfl(h2v, i, 32);
        acc3 = fmaf(hi, W3s[i * 32 + o], acc3);
    }
    out[(size_t)hw * 32 + o] = acc3;
}

// ---------------- Host launcher ----------------

extern "C" void kernel_launch(void* const* d_in, const int* in_sizes, int n_in,
                              void* d_out, int out_size, void* d_ws, size_t ws_size,
                              hipStream_t stream) {
    const int* src   = (const int*)d_in[0];
    const int* dst   = (const int*)d_in[1];
    const int* etype = (const int*)d_in[2];
    const float* W1  = (const float*)d_in[4];
    const float* b1  = (const float*)d_in[5];
    const float* W2  = (const float*)d_in[6];
    const float* b2  = (const float*)d_in[7];
    const float* W3  = (const float*)d_in[8];
    const float* b3  = (const float*)d_in[9];
    float* out = (float*)d_out;

    int E = in_sizes[0];
    int N = out_size / 32;
    int B = (N + NPB - 1) >> NPB_SHIFT;  // 391 for N=100000

    char* ws = (char*)d_ws;
    size_t off = 0;
    auto alloc = [&](size_t bytes) {
        void* p = ws + off;
        off = (off + bytes + 255) & ~(size_t)255;
        return p;
    };
    float* h1      = (float*)alloc((size_t)N * 32 * 4);
    int* bcnt      = (int*)alloc((size_t)MAXB * 4);
    int* pbase     = (int*)alloc((size_t)MAXB * 4);
    int* gcur      = (int*)alloc((size_t)MAXB * 4);
    int* row_start = (int*)alloc((size_t)N * 4);
    int* rend      = (int*)alloc((size_t)N * 4);
    uint2* recs    = (uint2*)alloc(((size_t)E + 8 * MAXB + 64) * 8);
    int* recs2     = (int*)alloc(((size_t)E + 8 * MAXB + 64) * 4);
    _Float16* g    = (_Float16*)alloc((size_t)NUM_RELS * N * 32 * 2);
    _Float16* W2F  = (_Float16*)alloc((size_t)NUM_RELS * 2 * 64 * 8 * 2);

    hipMemsetAsync(bcnt, 0, (size_t)B * 4, stream);
    bhist_kernel<<<256, 256, 0, stream>>>(dst, bcnt, E, B);
    bscan_kernel<<<1, 512, 0, stream>>>(bcnt, pbase, gcur, B);

    int chunk = (E + 127) / 128;
    partition_kernel<<<128, 512, 0, stream>>>(src, dst, etype, gcur, recs, E, B, chunk);

    bsort_kernel<<<B, 256, 0, stream>>>(recs, pbase, bcnt, recs2, row_start, rend, N);
    blayer1_kernel<<<B, 256, 0, stream>>>(recs, pbase, bcnt, W1, b1, h1, N);

    w2swz_kernel<<<(NUM_RELS * 2 * 64 * 8 + 255) / 256, 256, 0, stream>>>(W2, W2F);
    int ntiles = (N + 15) / 16;
    transform_kernel<<<(ntiles + 3) / 4, 256, 0, stream>>>(h1, W2F, g, N);

    edge23_kernel<<<(N + 31) / 32, 1024, 0, stream>>>(g, row_start, rend, recs2, b2, W3, b3, out, N);
}

// Round 10
// 261.674 us; speedup vs baseline: 2.2970x; 1.0312x over previous
//
#include <hip/hip_runtime.h>

#define NUM_RELS 19
#define NPB 256        // nodes per bucket (power of 2)
#define NPB_SHIFT 8
#define MAXB 400       // max buckets (N <= 102400)
#define PCAP 16        // partition stage capacity per bucket (flush in units of 8)

typedef _Float16 half8 __attribute__((ext_vector_type(8)));
typedef float floatx4 __attribute__((ext_vector_type(4)));

// ---------------- bucket histogram: bcnt[b] = #edges with dst in bucket b ----------------

__global__ __launch_bounds__(256) void bhist_kernel(const int* __restrict__ dst,
                                                    int* __restrict__ bcnt, int E, int B) {
    __shared__ int h[MAXB];
    for (int i = threadIdx.x; i < B; i += 256) h[i] = 0;
    __syncthreads();
    for (int e = blockIdx.x * blockDim.x + threadIdx.x; e < E; e += gridDim.x * blockDim.x)
        atomicAdd(&h[dst[e] >> NPB_SHIFT], 1);
    __syncthreads();
    for (int i = threadIdx.x; i < B; i += 256)
        if (h[i]) atomicAdd(&bcnt[i], h[i]);
}

// ---------------- bucket scan: pbase = exclusive scan of 8-aligned counts; gcur = pbase ----------------

__global__ __launch_bounds__(512) void bscan_kernel(const int* __restrict__ bcnt,
                                                    int* __restrict__ pbase,
                                                    int* __restrict__ gcur, int B) {
    __shared__ int lds[512];
    int t = threadIdx.x;
    int c = (t < B) ? ((bcnt[t] + 7) & ~7) : 0;
    lds[t] = c;
    __syncthreads();
    for (int off = 1; off < 512; off <<= 1) {
        int x = (t >= off) ? lds[t - off] : 0;
        __syncthreads();
        lds[t] += x;
        __syncthreads();
    }
    if (t < B) {
        int p = lds[t] - c;
        pbase[t] = p;
        gcur[t] = p;
    }
}

// ---------------- partition: bin edges into bucket regions with line-granular flushes ----------------
// Grid 384 (3 blocks/CU: 3x53.2KB LDS = 159.7KB <= 160KB). Round-9 ran grid=128 -> 9.6%
// occupancy, half the CUs idle, 25 barrier-synchronized rounds = 63us. 384 blocks cut
// rounds to ~8 per block; extra per-block drain tails cost a few MB of WRITE.

__global__ __launch_bounds__(512) void partition_kernel(
    const int* __restrict__ src, const int* __restrict__ dst, const int* __restrict__ etype,
    int* __restrict__ gcur, uint2* __restrict__ recs, int E, int B, int chunk) {
    __shared__ uint2 stage[MAXB * PCAP];  // 400*16*8B = 51.2KB
    __shared__ int scnt[MAXB];
    for (int i = threadIdx.x; i < B; i += 512) scnt[i] = 0;
    __syncthreads();

    int e0 = blockIdx.x * chunk;
    int e1 = min(E, e0 + chunk);
    for (int base = e0; base < e1; base += 512) {
        int e = base + (int)threadIdx.x;
        if (e < e1) {
            int d = dst[e];
            uint2 rec;
            rec.x = ((unsigned)src[e] << 5) | (unsigned)etype[e];
            rec.y = (unsigned)d;
            int b = d >> NPB_SHIFT;
            int pos = atomicAdd(&scnt[b], 1);
            if (pos < PCAP) {
                stage[b * PCAP + pos] = rec;
            } else {  // spill valve
                int g = atomicAdd(&gcur[b], 1);
                recs[g] = rec;
            }
        }
        __syncthreads();
        for (int bb = threadIdx.x; bb < B; bb += 512) {
            int c = scnt[bb];
            if (c > PCAP) c = PCAP;
            int nf = c & ~7;
            if (nf) {
                int g = atomicAdd(&gcur[bb], nf);
                for (int i = 0; i < nf; ++i) recs[g + i] = stage[bb * PCAP + i];
                for (int i = 0; i < c - nf; ++i) stage[bb * PCAP + i] = stage[bb * PCAP + nf + i];
            }
            scnt[bb] = c - nf;
        }
        __syncthreads();
    }
    // drain remainders
    for (int bb = threadIdx.x; bb < B; bb += 512) {
        int c = scnt[bb];
        if (c > PCAP) c = PCAP;
        if (c) {
            int g = atomicAdd(&gcur[bb], c);
            for (int i = 0; i < c; ++i) recs[g + i] = stage[bb * PCAP + i];
        }
    }
}

// ---------------- bucket-local counting sort + layer 1 (merged) ----------------
// Per bucket: (a) per-node + (node,rel) LDS histograms in ONE pass over recs,
// (b) scan -> row_start/rend/cur, (c) scatter recs -> recs2 (node-sorted, 4B; random writes
// confined to the bucket's ~16KB region -> L2 absorbs amplification),
// (d) h1[v] = relu(b1 + sum_r cnt2[v][r] * W1[r]) from the (node,rel) counts.
// Merging saves a full second 12.8MB pass over recs (round-9 ran these as two kernels).

__global__ __launch_bounds__(256) void bsort_l1_kernel(
    const uint2* __restrict__ recs, const int* __restrict__ pbase, const int* __restrict__ bcnt,
    int* __restrict__ recs2, int* __restrict__ row_start, int* __restrict__ rend,
    const float* __restrict__ W1, const float* __restrict__ b1, float* __restrict__ h1, int N) {
    __shared__ int hist[NPB];
    __shared__ int offs[NPB];
    __shared__ int cur[NPB];
    __shared__ int cnt2[NPB * NUM_RELS];  // 19.4KB
    __shared__ float W1s[NUM_RELS * 32];
    __shared__ float b1s[32];
    int b = blockIdx.x;
    int p0 = pbase[b], n = bcnt[b];
    int t = threadIdx.x;

    hist[t] = 0;
    for (int i = t; i < NPB * NUM_RELS; i += 256) cnt2[i] = 0;
    for (int i = t; i < NUM_RELS * 32; i += 256) W1s[i] = W1[i];
    if (t < 32) b1s[t] = b1[t];
    __syncthreads();

    for (int i = t; i < n; i += 256) {
        uint2 rec = recs[p0 + i];
        int ln = rec.y & (NPB - 1);
        atomicAdd(&hist[ln], 1);
        atomicAdd(&cnt2[ln * NUM_RELS + (rec.x & 31)], 1);
    }
    __syncthreads();
    int c = hist[t];
    offs[t] = c;
    __syncthreads();
    for (int off = 1; off < 256; off <<= 1) {
        int x = (t >= off) ? offs[t - off] : 0;
        __syncthreads();
        offs[t] += x;
        __syncthreads();
    }
    int start = p0 + offs[t] - c;  // exclusive
    cur[t] = start;
    int v = (b << NPB_SHIFT) + t;
    if (v < N) {
        row_start[v] = start;
        rend[v] = start + c;
    }
    __syncthreads();
    for (int i = t; i < n; i += 256) {
        uint2 rec = recs[p0 + i];  // L2-hot (just read above)
        int p = atomicAdd(&cur[rec.y & (NPB - 1)], 1);
        recs2[p] = (int)rec.x;
    }

    // layer 1 from cnt2 (no extra barrier needed beyond the one above; cnt2 final since
    // the first __syncthreads after the count pass)
    int o = t & 31, hw = t >> 5;  // 8 half-waves
    int v0 = b << NPB_SHIFT;
    for (int k = hw; k < NPB; k += 8) {
        int vv = v0 + k;
        if (vv >= N) break;
        float acc = b1s[o];
        const int* cp = &cnt2[k * NUM_RELS];
#pragma unroll
        for (int r = 0; r < NUM_RELS; ++r) acc += (float)cp[r] * W1s[r * 32 + o];
        h1[(size_t)vv * 32 + o] = fmaxf(acc, 0.f);
    }
}

// ---------------- W2 -> f16 B-fragment swizzle (round-6 verified) ----------------

__global__ void w2swz_kernel(const float* __restrict__ W2, _Float16* __restrict__ W2F) {
    int idx = blockIdx.x * blockDim.x + threadIdx.x;
    if (idx >= NUM_RELS * 2 * 64 * 8) return;
    int j = idx & 7, lane = (idx >> 3) & 63, nt = (idx >> 9) & 1, r = idx >> 10;
    int k = (lane >> 4) * 8 + j, n = nt * 16 + (lane & 15);
    W2F[idx] = (_Float16)W2[r * 1024 + k * 32 + n];
}

// ---------------- Transform via MFMA: g[r] = h1 @ W2[r]  (f16 output; round-6 verified) ----------------

__global__ __launch_bounds__(256) void transform_kernel(
    const float* __restrict__ h1, const _Float16* __restrict__ W2F,
    _Float16* __restrict__ g, int N) {
    int lane = threadIdx.x & 63;
    int tile = blockIdx.x * 4 + (threadIdx.x >> 6);
    int v0 = tile * 16;
    if (v0 >= N) return;

    const float* hrow = h1 + (size_t)(v0 + (lane & 15)) * 32 + (lane >> 4) * 8;
    float4 p0 = *(const float4*)hrow;
    float4 p1 = *(const float4*)(hrow + 4);
    half8 a;
    a[0] = (_Float16)p0.x; a[1] = (_Float16)p0.y; a[2] = (_Float16)p0.z; a[3] = (_Float16)p0.w;
    a[4] = (_Float16)p1.x; a[5] = (_Float16)p1.y; a[6] = (_Float16)p1.z; a[7] = (_Float16)p1.w;

    floatx4 zero = {0.f, 0.f, 0.f, 0.f};
    int row = (lane >> 4) * 4;
    int col = lane & 15;
    for (int r = 0; r < NUM_RELS; ++r) {
        _Float16* gbase = g + ((size_t)r * N + v0) * 32;
#pragma unroll
        for (int nt = 0; nt < 2; ++nt) {
            half8 bfrag = *(const half8*)(W2F + ((r * 2 + nt) * 64 + lane) * 8);
            floatx4 d = __builtin_amdgcn_mfma_f32_16x16x32_f16(a, bfrag, zero, 0, 0, 0);
#pragma unroll
            for (int reg = 0; reg < 4; ++reg) {
                gbase[(row + reg) * 32 + nt * 16 + col] = (_Float16)d[reg];
            }
        }
    }
}

// ---------------- Edge phase + layer 3 fused (round-9 verified: register accumulation) ----------------

__global__ __launch_bounds__(1024) void edge23_kernel(
    const _Float16* __restrict__ g, const int* __restrict__ row_start,
    const int* __restrict__ rend, const int* __restrict__ recs2,
    const float* __restrict__ b2, const float* __restrict__ W3, const float* __restrict__ b3,
    float* __restrict__ out, int N) {
    __shared__ float W3s[1024];
    __shared__ float b2s[32], b3s[32];
    W3s[threadIdx.x] = W3[threadIdx.x];
    if (threadIdx.x < 32) {
        b2s[threadIdx.x] = b2[threadIdx.x];
        b3s[threadIdx.x] = b3[threadIdx.x];
    }
    __syncthreads();

    int o = threadIdx.x & 31;
    int hw = blockIdx.x * 32 + (threadIdx.x >> 5);  // node id
    if (hw >= N) return;
    int start = row_start[hw], end = rend[hw];
    const size_t sN32 = (size_t)N * 32;

    float acc = b2s[o];
    for (int base = start; base < end; base += 32) {
        int idx = base + o;
        int m_l = (idx < end) ? recs2[idx] : 0;  // coalesced packed (src<<5|etype)
        int cnt = min(32, end - base);
        int j = 0;
        for (; j + 4 <= cnt; j += 4) {
            int m0 = __shfl(m_l, j + 0, 32);
            int m1 = __shfl(m_l, j + 1, 32);
            int m2 = __shfl(m_l, j + 2, 32);
            int m3 = __shfl(m_l, j + 3, 32);
            float x0 = (float)g[(size_t)(m0 & 31) * sN32 + (unsigned)(m0 >> 5) * 32 + o];
            float x1 = (float)g[(size_t)(m1 & 31) * sN32 + (unsigned)(m1 >> 5) * 32 + o];
            float x2 = (float)g[(size_t)(m2 & 31) * sN32 + (unsigned)(m2 >> 5) * 32 + o];
            float x3 = (float)g[(size_t)(m3 & 31) * sN32 + (unsigned)(m3 >> 5) * 32 + o];
            acc += (x0 + x1) + (x2 + x3);
        }
        for (; j < cnt; ++j) {
            int m = __shfl(m_l, j, 32);
            acc += (float)g[(size_t)(m & 31) * sN32 + (unsigned)(m >> 5) * 32 + o];
        }
    }
    float h2v = fmaxf(acc, 0.f);

    float acc3 = b3s[o];
#pragma unroll
    for (int i = 0; i < 32; ++i) {
        float hi = __shfl(h2v, i, 32);
        acc3 = fmaf(hi, W3s[i * 32 + o], acc3);
    }
    out[(size_t)hw * 32 + o] = acc3;
}

// ---------------- Host launcher ----------------

extern "C" void kernel_launch(void* const* d_in, const int* in_sizes, int n_in,
                              void* d_out, int out_size, void* d_ws, size_t ws_size,
                              hipStream_t stream) {
    const int* src   = (const int*)d_in[0];
    const int* dst   = (const int*)d_in[1];
    const int* etype = (const int*)d_in[2];
    const float* W1  = (const float*)d_in[4];
    const float* b1  = (const float*)d_in[5];
    const float* W2  = (const float*)d_in[6];
    const float* b2  = (const float*)d_in[7];
    const float* W3  = (const float*)d_in[8];
    const float* b3  = (const float*)d_in[9];
    float* out = (float*)d_out;

    int E = in_sizes[0];
    int N = out_size / 32;
    int B = (N + NPB - 1) >> NPB_SHIFT;  // 391 for N=100000

    char* ws = (char*)d_ws;
    size_t off = 0;
    auto alloc = [&](size_t bytes) {
        void* p = ws + off;
        off = (off + bytes + 255) & ~(size_t)255;
        return p;
    };
    float* h1      = (float*)alloc((size_t)N * 32 * 4);
    int* bcnt      = (int*)alloc((size_t)MAXB * 4);
    int* pbase     = (int*)alloc((size_t)MAXB * 4);
    int* gcur      = (int*)alloc((size_t)MAXB * 4);
    int* row_start = (int*)alloc((size_t)N * 4);
    int* rend      = (int*)alloc((size_t)N * 4);
    uint2* recs    = (uint2*)alloc(((size_t)E + 8 * MAXB + 64) * 8);
    int* recs2     = (int*)alloc(((size_t)E + 8 * MAXB + 64) * 4);
    _Float16* g    = (_Float16*)alloc((size_t)NUM_RELS * N * 32 * 2);
    _Float16* W2F  = (_Float16*)alloc((size_t)NUM_RELS * 2 * 64 * 8 * 2);

    hipMemsetAsync(bcnt, 0, (size_t)B * 4, stream);
    bhist_kernel<<<256, 256, 0, stream>>>(dst, bcnt, E, B);
    bscan_kernel<<<1, 512, 0, stream>>>(bcnt, pbase, gcur, B);

    const int PGRID = 384;  // 3 blocks/CU by LDS (53.2KB); round-9's 128 left half the chip idle
    int chunk = (E + PGRID - 1) / PGRID;
    partition_kernel<<<PGRID, 512, 0, stream>>>(src, dst, etype, gcur, recs, E, B, chunk);

    bsort_l1_kernel<<<B, 256, 0, stream>>>(recs, pbase, bcnt, recs2, row_start, rend,
                                           W1, b1, h1, N);

    w2swz_kernel<<<(NUM_RELS * 2 * 64 * 8 + 255) / 256, 256, 0, stream>>>(W2, W2F);
    int ntiles = (N + 15) / 16;
    transform_kernel<<<(ntiles + 3) / 4, 256, 0, stream>>>(h1, W2F, g, N);

    edge23_kernel<<<(N + 31) / 32, 1024, 0, stream>>>(g, row_start, rend, recs2, b2, W3, b3, out, N);
}

// Round 11
// 239.083 us; speedup vs baseline: 2.5141x; 1.0945x over previous
//
#include <hip/hip_runtime.h>

#define NUM_RELS 19
#define NPB 256        // nodes per bucket (power of 2)
#define NPB_SHIFT 8
#define MAXB 400       // max buckets (N <= 102400)
#define NBLK 512       // partition chunk-blocks (2 blocks/CU)

typedef _Float16 half8 __attribute__((ext_vector_type(8)));
typedef float floatx4 __attribute__((ext_vector_type(4)));

// ---------------- pass A: per-block bucket histogram (also produces bcnt totals) ----------------

__global__ __launch_bounds__(512) void count_kernel(const int* __restrict__ dst,
                                                    int* __restrict__ blkhist,
                                                    int* __restrict__ bcnt,
                                                    int E, int B, int chunk) {
    __shared__ int h[MAXB];
    for (int i = threadIdx.x; i < B; i += 512) h[i] = 0;
    __syncthreads();
    int e0 = blockIdx.x * chunk, e1 = min(E, e0 + chunk);
    for (int e = e0 + (int)threadIdx.x; e < e1; e += 512)
        atomicAdd(&h[dst[e] >> NPB_SHIFT], 1);
    __syncthreads();
    for (int i = threadIdx.x; i < B; i += 512) {
        blkhist[blockIdx.x * B + i] = h[i];  // [block][bucket]: contiguous writes
        if (h[i]) atomicAdd(&bcnt[i], h[i]);
    }
}

// ---------------- bucket scan: pbase = exclusive scan of 8-aligned counts ----------------

__global__ __launch_bounds__(512) void bscan_kernel(const int* __restrict__ bcnt,
                                                    int* __restrict__ pbase, int B) {
    __shared__ int lds[512];
    int t = threadIdx.x;
    int c = (t < B) ? ((bcnt[t] + 7) & ~7) : 0;
    lds[t] = c;
    __syncthreads();
    for (int off = 1; off < 512; off <<= 1) {
        int x = (t >= off) ? lds[t - off] : 0;
        __syncthreads();
        lds[t] += x;
        __syncthreads();
    }
    if (t < B) pbase[t] = lds[t] - c;
}

// ---------------- pass B prep: per-bucket scan across chunk-blocks -> deterministic offsets ----------------
// offs[block][bucket] = pbase[bucket] + sum_{blk' < block} blkhist[blk'][bucket].
// Strided reads/writes (stride B*4) but total data 512*391*4 = 600KB -> L2-absorbed.

__global__ __launch_bounds__(NBLK) void offscan_kernel(const int* __restrict__ blkhist,
                                                       const int* __restrict__ pbase,
                                                       int* __restrict__ offs, int B) {
    __shared__ int lds[NBLK];
    int bucket = blockIdx.x;
    int t = threadIdx.x;
    int v = blkhist[t * B + bucket];
    lds[t] = v;
    __syncthreads();
    for (int off = 1; off < NBLK; off <<= 1) {
        int x = (t >= off) ? lds[t - off] : 0;
        __syncthreads();
        lds[t] += x;
        __syncthreads();
    }
    offs[t * B + bucket] = pbase[bucket] + lds[t] - v;
}

// ---------------- pass B: scatter with deterministic offsets ----------------
// LDS cursors start at this block's exact region per bucket: rank via LDS atomic, ONE direct
// global 8B store per record. No global atomics, no barrier rounds (round-10's partition spent
// 58us in serialized flush chains). Streaming loop -> memory-speed.

__global__ __launch_bounds__(512) void scatter2_kernel(
    const int* __restrict__ src, const int* __restrict__ dst, const int* __restrict__ etype,
    const int* __restrict__ offs, uint2* __restrict__ recs, int E, int B, int chunk) {
    __shared__ int cur[MAXB];
    for (int i = threadIdx.x; i < B; i += 512) cur[i] = offs[blockIdx.x * B + i];
    __syncthreads();
    int e0 = blockIdx.x * chunk, e1 = min(E, e0 + chunk);
    for (int e = e0 + (int)threadIdx.x; e < e1; e += 512) {
        int d = dst[e];
        int b = d >> NPB_SHIFT;
        int pos = atomicAdd(&cur[b], 1);  // LDS atomic: rank within (block,bucket)
        uint2 rec;
        rec.x = ((unsigned)src[e] << 5) | (unsigned)etype[e];
        rec.y = (unsigned)d;
        recs[pos] = rec;
    }
}

// ---------------- bucket-local counting sort + layer 1 (merged; round-10 verified) ----------------

__global__ __launch_bounds__(256) void bsort_l1_kernel(
    const uint2* __restrict__ recs, const int* __restrict__ pbase, const int* __restrict__ bcnt,
    int* __restrict__ recs2, int* __restrict__ row_start, int* __restrict__ rend,
    const float* __restrict__ W1, const float* __restrict__ b1, float* __restrict__ h1, int N) {
    __shared__ int hist[NPB];
    __shared__ int offsl[NPB];
    __shared__ int cur[NPB];
    __shared__ int cnt2[NPB * NUM_RELS];  // 19.4KB
    __shared__ float W1s[NUM_RELS * 32];
    __shared__ float b1s[32];
    int b = blockIdx.x;
    int p0 = pbase[b], n = bcnt[b];
    int t = threadIdx.x;

    hist[t] = 0;
    for (int i = t; i < NPB * NUM_RELS; i += 256) cnt2[i] = 0;
    for (int i = t; i < NUM_RELS * 32; i += 256) W1s[i] = W1[i];
    if (t < 32) b1s[t] = b1[t];
    __syncthreads();

    for (int i = t; i < n; i += 256) {
        uint2 rec = recs[p0 + i];
        int ln = rec.y & (NPB - 1);
        atomicAdd(&hist[ln], 1);
        atomicAdd(&cnt2[ln * NUM_RELS + (rec.x & 31)], 1);
    }
    __syncthreads();
    int c = hist[t];
    offsl[t] = c;
    __syncthreads();
    for (int off = 1; off < 256; off <<= 1) {
        int x = (t >= off) ? offsl[t - off] : 0;
        __syncthreads();
        offsl[t] += x;
        __syncthreads();
    }
    int start = p0 + offsl[t] - c;  // exclusive
    cur[t] = start;
    int v = (b << NPB_SHIFT) + t;
    if (v < N) {
        row_start[v] = start;
        rend[v] = start + c;
    }
    __syncthreads();
    for (int i = t; i < n; i += 256) {
        uint2 rec = recs[p0 + i];  // L2-hot (just read above)
        int p = atomicAdd(&cur[rec.y & (NPB - 1)], 1);
        recs2[p] = (int)rec.x;
    }

    int o = t & 31, hw = t >> 5;  // 8 half-waves
    int v0 = b << NPB_SHIFT;
    for (int k = hw; k < NPB; k += 8) {
        int vv = v0 + k;
        if (vv >= N) break;
        float acc = b1s[o];
        const int* cp = &cnt2[k * NUM_RELS];
#pragma unroll
        for (int r = 0; r < NUM_RELS; ++r) acc += (float)cp[r] * W1s[r * 32 + o];
        h1[(size_t)vv * 32 + o] = fmaxf(acc, 0.f);
    }
}

// ---------------- W2 -> f16 B-fragment swizzle (round-6 verified) ----------------

__global__ void w2swz_kernel(const float* __restrict__ W2, _Float16* __restrict__ W2F) {
    int idx = blockIdx.x * blockDim.x + threadIdx.x;
    if (idx >= NUM_RELS * 2 * 64 * 8) return;
    int j = idx & 7, lane = (idx >> 3) & 63, nt = (idx >> 9) & 1, r = idx >> 10;
    int k = (lane >> 4) * 8 + j, n = nt * 16 + (lane & 15);
    W2F[idx] = (_Float16)W2[r * 1024 + k * 32 + n];
}

// ---------------- Transform via MFMA: g[r] = h1 @ W2[r]  (f16 output; round-6 verified) ----------------

__global__ __launch_bounds__(256) void transform_kernel(
    const float* __restrict__ h1, const _Float16* __restrict__ W2F,
    _Float16* __restrict__ g, int N) {
    int lane = threadIdx.x & 63;
    int tile = blockIdx.x * 4 + (threadIdx.x >> 6);
    int v0 = tile * 16;
    if (v0 >= N) return;

    const float* hrow = h1 + (size_t)(v0 + (lane & 15)) * 32 + (lane >> 4) * 8;
    float4 p0 = *(const float4*)hrow;
    float4 p1 = *(const float4*)(hrow + 4);
    half8 a;
    a[0] = (_Float16)p0.x; a[1] = (_Float16)p0.y; a[2] = (_Float16)p0.z; a[3] = (_Float16)p0.w;
    a[4] = (_Float16)p1.x; a[5] = (_Float16)p1.y; a[6] = (_Float16)p1.z; a[7] = (_Float16)p1.w;

    floatx4 zero = {0.f, 0.f, 0.f, 0.f};
    int row = (lane >> 4) * 4;
    int col = lane & 15;
    for (int r = 0; r < NUM_RELS; ++r) {
        _Float16* gbase = g + ((size_t)r * N + v0) * 32;
#pragma unroll
        for (int nt = 0; nt < 2; ++nt) {
            half8 bfrag = *(const half8*)(W2F + ((r * 2 + nt) * 64 + lane) * 8);
            floatx4 d = __builtin_amdgcn_mfma_f32_16x16x32_f16(a, bfrag, zero, 0, 0, 0);
#pragma unroll
            for (int reg = 0; reg < 4; ++reg) {
                gbase[(row + reg) * 32 + nt * 16 + col] = (_Float16)d[reg];
            }
        }
    }
}

// ---------------- Edge phase + layer 3 fused (round-9 verified: register accumulation) ----------------

__global__ __launch_bounds__(1024) void edge23_kernel(
    const _Float16* __restrict__ g, const int* __restrict__ row_start,
    const int* __restrict__ rend, const int* __restrict__ recs2,
    const float* __restrict__ b2, const float* __restrict__ W3, const float* __restrict__ b3,
    float* __restrict__ out, int N) {
    __shared__ float W3s[1024];
    __shared__ float b2s[32], b3s[32];
    W3s[threadIdx.x] = W3[threadIdx.x];
    if (threadIdx.x < 32) {
        b2s[threadIdx.x] = b2[threadIdx.x];
        b3s[threadIdx.x] = b3[threadIdx.x];
    }
    __syncthreads();

    int o = threadIdx.x & 31;
    int hw = blockIdx.x * 32 + (threadIdx.x >> 5);  // node id
    if (hw >= N) return;
    int start = row_start[hw], end = rend[hw];
    const size_t sN32 = (size_t)N * 32;

    float acc = b2s[o];
    for (int base = start; base < end; base += 32) {
        int idx = base + o;
        int m_l = (idx < end) ? recs2[idx] : 0;  // coalesced packed (src<<5|etype)
        int cnt = min(32, end - base);
        int j = 0;
        for (; j + 4 <= cnt; j += 4) {
            int m0 = __shfl(m_l, j + 0, 32);
            int m1 = __shfl(m_l, j + 1, 32);
            int m2 = __shfl(m_l, j + 2, 32);
            int m3 = __shfl(m_l, j + 3, 32);
            float x0 = (float)g[(size_t)(m0 & 31) * sN32 + (unsigned)(m0 >> 5) * 32 + o];
            float x1 = (float)g[(size_t)(m1 & 31) * sN32 + (unsigned)(m1 >> 5) * 32 + o];
            float x2 = (float)g[(size_t)(m2 & 31) * sN32 + (unsigned)(m2 >> 5) * 32 + o];
            float x3 = (float)g[(size_t)(m3 & 31) * sN32 + (unsigned)(m3 >> 5) * 32 + o];
            acc += (x0 + x1) + (x2 + x3);
        }
        for (; j < cnt; ++j) {
            int m = __shfl(m_l, j, 32);
            acc += (float)g[(size_t)(m & 31) * sN32 + (unsigned)(m >> 5) * 32 + o];
        }
    }
    float h2v = fmaxf(acc, 0.f);

    float acc3 = b3s[o];
#pragma unroll
    for (int i = 0; i < 32; ++i) {
        float hi = __shfl(h2v, i, 32);
        acc3 = fmaf(hi, W3s[i * 32 + o], acc3);
    }
    out[(size_t)hw * 32 + o] = acc3;
}

// ---------------- Host launcher ----------------

extern "C" void kernel_launch(void* const* d_in, const int* in_sizes, int n_in,
                              void* d_out, int out_size, void* d_ws, size_t ws_size,
                              hipStream_t stream) {
    const int* src   = (const int*)d_in[0];
    const int* dst   = (const int*)d_in[1];
    const int* etype = (const int*)d_in[2];
    const float* W1  = (const float*)d_in[4];
    const float* b1  = (const float*)d_in[5];
    const float* W2  = (const float*)d_in[6];
    const float* b2  = (const float*)d_in[7];
    const float* W3  = (const float*)d_in[8];
    const float* b3  = (const float*)d_in[9];
    float* out = (float*)d_out;

    int E = in_sizes[0];
    int N = out_size / 32;
    int B = (N + NPB - 1) >> NPB_SHIFT;  // 391 for N=100000

    char* ws = (char*)d_ws;
    size_t off = 0;
    auto alloc = [&](size_t bytes) {
        void* p = ws + off;
        off = (off + bytes + 255) & ~(size_t)255;
        return p;
    };
    float* h1      = (float*)alloc((size_t)N * 32 * 4);
    int* bcnt      = (int*)alloc((size_t)MAXB * 4);
    int* pbase     = (int*)alloc((size_t)MAXB * 4);
    int* blkhist   = (int*)alloc((size_t)NBLK * MAXB * 4);
    int* offs      = (int*)alloc((size_t)NBLK * MAXB * 4);
    int* row_start = (int*)alloc((size_t)N * 4);
    int* rend      = (int*)alloc((size_t)N * 4);
    uint2* recs    = (uint2*)alloc(((size_t)E + 8 * MAXB + 64) * 8);
    int* recs2     = (int*)alloc(((size_t)E + 8 * MAXB + 64) * 4);
    _Float16* g    = (_Float16*)alloc((size_t)NUM_RELS * N * 32 * 2);
    _Float16* W2F  = (_Float16*)alloc((size_t)NUM_RELS * 2 * 64 * 8 * 2);

    hipMemsetAsync(bcnt, 0, (size_t)B * 4, stream);

    int chunk = (E + NBLK - 1) / NBLK;
    count_kernel<<<NBLK, 512, 0, stream>>>(dst, blkhist, bcnt, E, B, chunk);
    bscan_kernel<<<1, 512, 0, stream>>>(bcnt, pbase, B);
    offscan_kernel<<<B, NBLK, 0, stream>>>(blkhist, pbase, offs, B);
    scatter2_kernel<<<NBLK, 512, 0, stream>>>(src, dst, etype, offs, recs, E, B, chunk);

    bsort_l1_kernel<<<B, 256, 0, stream>>>(recs, pbase, bcnt, recs2, row_start, rend,
                                           W1, b1, h1, N);

    w2swz_kernel<<<(NUM_RELS * 2 * 64 * 8 + 255) / 256, 256, 0, stream>>>(W2, W2F);
    int ntiles = (N + 15) / 16;
    transform_kernel<<<(ntiles + 3) / 4, 256, 0, stream>>>(h1, W2F, g, N);

    edge23_kernel<<<(N + 31) / 32, 1024, 0, stream>>>(g, row_start, rend, recs2, b2, W3, b3, out, N);
}